// Round 1
// baseline (571.412 us; speedup 1.0000x reference)
//
#include <hip/hip_runtime.h>
#include <stdint.h>

// Problem constants (from reference)
#define ENC_D 512
#define STR_D 256
#define CELL_D 512
#define ATTN_D 512
#define BATCH 64
#define SEQ 1024
#define NROWS (BATCH * SEQ)   // 65536

typedef __bf16 bf16x8 __attribute__((ext_vector_type(8)));
typedef float f32x4 __attribute__((ext_vector_type(4)));

__device__ __forceinline__ unsigned short f2bf(float f) {
    unsigned int u = __float_as_uint(f);
    u += 0x7fffu + ((u >> 16) & 1u);   // round-to-nearest-even
    return (unsigned short)(u >> 16);
}

// ---------------------------------------------------------------------------
// Kernel 1: WT[a][e] = bf16(W_enc[e][a])   (transpose + convert, 512x512)
// ---------------------------------------------------------------------------
__global__ __launch_bounds__(256) void k_prep_wt(const float* __restrict__ W,
                                                 unsigned short* __restrict__ WT) {
    int idx = blockIdx.x * 256 + threadIdx.x;  // idx = a*512 + e
    int a = idx >> 9, e = idx & 511;
    WT[idx] = f2bf(W[e * ATTN_D + a]);
}

// ---------------------------------------------------------------------------
// Kernel 2: bias[b][a] = b_enc[a] + str[b]@W_str + b_str[a] + cell[b]@W_cell + b_cell[a]
// fp32 end to end. 64 blocks x 256 threads; each thread does 2 'a' columns.
// ---------------------------------------------------------------------------
__global__ __launch_bounds__(256) void k_bias(const float* __restrict__ str,
                                              const float* __restrict__ cell,
                                              const float* __restrict__ b_enc,
                                              const float* __restrict__ Wstr,
                                              const float* __restrict__ b_str,
                                              const float* __restrict__ Wcell,
                                              const float* __restrict__ b_cell,
                                              float* __restrict__ bias) {
    const int b = blockIdx.x, t = threadIdx.x;
    for (int h = 0; h < 2; ++h) {
        const int a = t + h * 256;
        float acc = b_enc[a] + b_str[a] + b_cell[a];
        for (int j = 0; j < STR_D; ++j)
            acc += str[b * STR_D + j] * Wstr[j * ATTN_D + a];
        for (int j = 0; j < CELL_D; ++j)
            acc += cell[b * CELL_D + j] * Wcell[j * ATTN_D + a];
        bias[b * ATTN_D + a] = acc;
    }
}

// ---------------------------------------------------------------------------
// Kernel 3: fused scores GEMM.
//   scores[r] = sum_a relu( E[r,:] @ W_enc[:,a] + bias[b][a] ) * W_comb[a]
// Block = 256 threads (4 waves), M-tile = 64 rows (16 rows/wave).
// E tile staged to LDS as bf16, XOR-swizzled (64KiB exactly, 2-way max conflict).
// N looped in 8 chunks of 64; per chunk each wave does 4 MFMA column-tiles.
// ---------------------------------------------------------------------------
__global__ __launch_bounds__(256, 2) void k_scores(const float* __restrict__ E,
                                                   const unsigned short* __restrict__ WT,
                                                   const float* __restrict__ bias,
                                                   const float* __restrict__ Wcomb,
                                                   float* __restrict__ scores) {
    extern __shared__ unsigned char smem[];
    unsigned short* Eld = (unsigned short*)smem;   // 64 rows x 512 cols (swizzled)

    const int tid = threadIdx.x;
    const int r0 = blockIdx.x * 64;       // first global row of this tile
    const int b = blockIdx.x >> 4;        // 16 blocks per batch (1024/64)

    // ---- stage E tile: 64 x 512 fp32 -> bf16 LDS, XOR swizzle on 8-elem groups
    const float* Eb = E + (size_t)r0 * ENC_D;
#pragma unroll
    for (int i = 0; i < 32; ++i) {
        const int f = tid + i * 256;          // 0..8191 float4 slots
        const int row = f >> 7, c4 = f & 127; // 128 float4 per row
        const float4 v = *(const float4*)(Eb + (size_t)row * ENC_D + c4 * 4);
        ushort4 o;
        o.x = f2bf(v.x); o.y = f2bf(v.y); o.z = f2bf(v.z); o.w = f2bf(v.w);
        const int col = c4 * 4;
        const int g = col >> 3, sub = col & 7;
        const int scol = ((g ^ (row & 7)) << 3) + sub;
        *(ushort4*)(&Eld[row * 512 + scol]) = o;
    }
    __syncthreads();

    const int w = tid >> 6, lane = tid & 63;
    const int quad = lane >> 4, c = lane & 15;
    const int arow = w * 16 + c;              // A-operand row for this lane
    const unsigned short* Abase = &Eld[arow * 512];
    const int rsw = arow & 7;

    float sc[4] = {0.f, 0.f, 0.f, 0.f};      // per-lane partial scores, rows quad*4+r

    const float* biasb = bias + b * ATTN_D;

    for (int chunk = 0; chunk < 8; ++chunk) {
        const int n0 = chunk * 64;
        f32x4 acc[4] = {{0.f,0.f,0.f,0.f},{0.f,0.f,0.f,0.f},
                        {0.f,0.f,0.f,0.f},{0.f,0.f,0.f,0.f}};
        // B-frag base: WT[n][k], n = n0 + t*16 + c, k = ks*32 + quad*8
        const unsigned short* Wb = WT + (size_t)(n0 + c) * ENC_D + quad * 8;
#pragma unroll 4
        for (int ks = 0; ks < 16; ++ks) {
            const int g0 = ks * 4 + quad;  // k-group index
            bf16x8 afrag = *(const bf16x8*)(Abase + ((g0 ^ rsw) << 3));
#pragma unroll
            for (int t = 0; t < 4; ++t) {
                bf16x8 bfrag = *(const bf16x8*)(Wb + t * (16 * ENC_D) + ks * 32);
                acc[t] = __builtin_amdgcn_mfma_f32_16x16x32_bf16(afrag, bfrag, acc[t], 0, 0, 0);
            }
        }
        // epilogue: bias + relu + dot with W_comb, accumulate per-lane
#pragma unroll
        for (int t = 0; t < 4; ++t) {
            const int n = n0 + t * 16 + c;
            const float bi = biasb[n];
            const float wcn = Wcomb[n];
#pragma unroll
            for (int r = 0; r < 4; ++r) {
                float v = acc[t][r] + bi;
                v = v > 0.f ? v : 0.f;
                sc[r] += v * wcn;
            }
        }
    }

    // reduce across the 16 column-lanes (same quad group)
#pragma unroll
    for (int r = 0; r < 4; ++r) {
        float v = sc[r];
        v += __shfl_xor(v, 1);
        v += __shfl_xor(v, 2);
        v += __shfl_xor(v, 4);
        v += __shfl_xor(v, 8);
        sc[r] = v;
    }
    if (c == 0) {
        const int grow = r0 + w * 16 + quad * 4;
#pragma unroll
        for (int r = 0; r < 4; ++r) scores[grow + r] = sc[r];
    }
}

// ---------------------------------------------------------------------------
// Kernel 4: softmax over L=1024 per batch, in place (scores -> weights)
// ---------------------------------------------------------------------------
__global__ __launch_bounds__(256) void k_softmax(float* __restrict__ s) {
    __shared__ float red[256];
    const int b = blockIdx.x, t = threadIdx.x;
    float v[4];
    float m = -1e30f;
#pragma unroll
    for (int i = 0; i < 4; ++i) {
        v[i] = s[b * SEQ + i * 256 + t];
        m = fmaxf(m, v[i]);
    }
    red[t] = m;
    __syncthreads();
    for (int o = 128; o > 0; o >>= 1) {
        if (t < o) red[t] = fmaxf(red[t], red[t + o]);
        __syncthreads();
    }
    m = red[0];
    __syncthreads();
    float sum = 0.f;
#pragma unroll
    for (int i = 0; i < 4; ++i) {
        v[i] = __expf(v[i] - m);
        sum += v[i];
    }
    red[t] = sum;
    __syncthreads();
    for (int o = 128; o > 0; o >>= 1) {
        if (t < o) red[t] += red[t + o];
        __syncthreads();
    }
    const float inv = 1.f / red[0];
#pragma unroll
    for (int i = 0; i < 4; ++i) s[b * SEQ + i * 256 + t] = v[i] * inv;
}

// ---------------------------------------------------------------------------
// Kernel 5: context partials. Block z: batch b = z>>3, ec = (z&7)>>2 selects
// 256-wide ENC chunk, lq = z&3 selects 256-long L quarter.
// part[b][lq][e] = sum_{l in quarter} w[b,l] * E[b,l,e]
// ---------------------------------------------------------------------------
__global__ __launch_bounds__(256) void k_context(const float* __restrict__ E,
                                                 const float* __restrict__ wts,
                                                 float* __restrict__ part) {
    __shared__ float wl[256];
    const int z = blockIdx.x, t = threadIdx.x;
    const int b = z >> 3, r = z & 7, ec = r >> 2, lq = r & 3;
    wl[t] = wts[b * SEQ + lq * 256 + t];
    __syncthreads();
    const int e = ec * 256 + t;
    const float* Ep = E + ((size_t)(b * SEQ + lq * 256)) * ENC_D + e;
    float acc = 0.f;
#pragma unroll 8
    for (int l = 0; l < 256; ++l) acc += wl[l] * Ep[(size_t)l * ENC_D];
    part[(b * 4 + lq) * ENC_D + e] = acc;
}

// ---------------------------------------------------------------------------
// Kernel 6: final reduce of 4 L-quarter partials -> out[b][e]
// ---------------------------------------------------------------------------
__global__ __launch_bounds__(256) void k_reduce(const float* __restrict__ part,
                                                float* __restrict__ out) {
    const int idx = blockIdx.x * 256 + threadIdx.x;  // 0..32767
    const int b = idx >> 9, e = idx & 511;
    out[idx] = part[(b * 4 + 0) * ENC_D + e] + part[(b * 4 + 1) * ENC_D + e] +
               part[(b * 4 + 2) * ENC_D + e] + part[(b * 4 + 3) * ENC_D + e];
}

// ---------------------------------------------------------------------------
extern "C" void kernel_launch(void* const* d_in, const int* in_sizes, int n_in,
                              void* d_out, int out_size, void* d_ws, size_t ws_size,
                              hipStream_t stream) {
    const float* E      = (const float*)d_in[0];
    const float* str    = (const float*)d_in[1];   // [1,B,256]
    const float* cell   = (const float*)d_in[2];   // [1,B,512]
    const float* Wenc   = (const float*)d_in[3];
    const float* b_enc  = (const float*)d_in[4];
    const float* Wstr   = (const float*)d_in[5];
    const float* b_str  = (const float*)d_in[6];
    const float* Wcell  = (const float*)d_in[7];
    const float* b_cell = (const float*)d_in[8];
    const float* Wcomb  = (const float*)d_in[9];
    // d_in[10] = b_comb: uniform shift before softmax -> no effect, skipped.
    float* out = (float*)d_out;

    char* ws = (char*)d_ws;
    unsigned short* WT = (unsigned short*)ws;                       // 512 KB
    float* bias   = (float*)(ws + 524288);                          // 128 KB
    float* scores = (float*)(ws + 524288 + 131072);                 // 256 KB
    float* part   = (float*)(ws + 524288 + 131072 + 262144);        // 512 KB

    k_prep_wt<<<1024, 256, 0, stream>>>(Wenc, WT);
    k_bias<<<64, 256, 0, stream>>>(str, cell, b_enc, Wstr, b_str, Wcell, b_cell, bias);
    k_scores<<<NROWS / 64, 256, 64 * 512 * 2, stream>>>(E, WT, bias, Wcomb, scores);
    k_softmax<<<BATCH, 256, 0, stream>>>(scores);
    k_context<<<512, 256, 0, stream>>>(E, scores, part);
    k_reduce<<<NROWS / 512, 256, 0, stream>>>(part, out);
}

// Round 2
// 382.084 us; speedup vs baseline: 1.4955x; 1.4955x over previous
//
#include <hip/hip_runtime.h>
#include <stdint.h>

#define ENC_D 512
#define ATTN_D 512
#define STR_D 256
#define CELL_D 512
#define BATCH 64
#define SEQ 1024
#define NROWS (BATCH * SEQ)

typedef __bf16 bf16x8 __attribute__((ext_vector_type(8)));
typedef float f32x4 __attribute__((ext_vector_type(4)));

__device__ __forceinline__ unsigned short f2bf(float f) {
    unsigned int u = __float_as_uint(f);
    u += 0x7fffu + ((u >> 16) & 1u);   // RNE
    return (unsigned short)(u >> 16);
}

__device__ __forceinline__ void lds_cp16(void* l, const void* g) {
    __builtin_amdgcn_global_load_lds(
        (const __attribute__((address_space(1))) unsigned int*)g,
        (__attribute__((address_space(3))) unsigned int*)l, 16, 0, 0);
}

// ---------------------------------------------------------------------------
// Kernel 1: WT_sw — bf16(W_enc^T), pre-swizzled so a FLAT copy into LDS yields
// an XOR-swizzled image. Granule = 8 elems (16 B). For column n, k-group g:
//   chunk = n>>5 (32-col chunks), colc = n&31
//   slot within chunk = colc*64 + (g ^ (colc&7))
// ---------------------------------------------------------------------------
__global__ __launch_bounds__(256) void k_prep_wt(const float* __restrict__ W,
                                                 unsigned short* __restrict__ WT) {
    const int idx = blockIdx.x * 256 + threadIdx.x;   // granule id = n*64 + g
    const int n = idx >> 6, g = idx & 63;
    const int chunk = n >> 5, colc = n & 31;
    const int slot = colc * 64 + (g ^ (colc & 7));
    union { unsigned short s[8]; uint4 u; } o;
#pragma unroll
    for (int j = 0; j < 8; ++j) o.s[j] = f2bf(W[(g * 8 + j) * ATTN_D + n]);
    *(uint4*)(WT + (size_t)chunk * 16384 + slot * 8) = o.u;
}

// ---------------------------------------------------------------------------
// Kernel 2: bias[b][a] (fp32)
// ---------------------------------------------------------------------------
__global__ __launch_bounds__(256) void k_bias(const float* __restrict__ str,
                                              const float* __restrict__ cell,
                                              const float* __restrict__ b_enc,
                                              const float* __restrict__ Wstr,
                                              const float* __restrict__ b_str,
                                              const float* __restrict__ Wcell,
                                              const float* __restrict__ b_cell,
                                              float* __restrict__ bias) {
    const int b = blockIdx.x, t = threadIdx.x;
    for (int h = 0; h < 2; ++h) {
        const int a = t + h * 256;
        float acc = b_enc[a] + b_str[a] + b_cell[a];
        for (int j = 0; j < STR_D; ++j)
            acc += str[b * STR_D + j] * Wstr[j * ATTN_D + a];
        for (int j = 0; j < CELL_D; ++j)
            acc += cell[b * CELL_D + j] * Wcell[j * ATTN_D + a];
        bias[b * ATTN_D + a] = acc;
    }
}

// ---------------------------------------------------------------------------
// Kernel 3: fused scores GEMM. 512 blocks x 512 threads (8 waves), M=128/block.
// A (E rows) held in registers (16 bf16x8/lane); W double-buffered in LDS via
// async global_load_lds of the pre-swizzled WT_sw; 16 N-chunks of 32 cols.
// ---------------------------------------------------------------------------
__global__ __launch_bounds__(512, 4) void k_scores(const float* __restrict__ E,
                                                   const unsigned short* __restrict__ WTsw,
                                                   const float* __restrict__ bias,
                                                   const float* __restrict__ Wcomb,
                                                   float* __restrict__ scores) {
    __shared__ unsigned short wlds[2][16384];   // 2 x 32 KB

    const int tid = threadIdx.x;
    const int r0 = blockIdx.x * 128;
    const int b = blockIdx.x >> 3;              // 8 blocks per batch
    const int w = tid >> 6, lane = tid & 63;
    const int quad = lane >> 4, c = lane & 15;

    // ---- stage W chunk 0 (async) ----
    {
        const char* gsrc = (const char*)WTsw;   // chunk 0
        char* ldst = (char*)&wlds[0][0];
#pragma unroll
        for (int i = 0; i < 4; ++i)
            lds_cp16(ldst + i * 8192 + tid * 16, gsrc + i * 8192 + tid * 16);
    }

    // ---- load A fragments: 16 rows/wave, full K in regs ----
    bf16x8 afr[16];
    {
        const float* Ep = E + (size_t)(r0 + w * 16 + c) * ENC_D + quad * 8;
#pragma unroll
        for (int ks = 0; ks < 16; ++ks) {
            const float4 v0 = *(const float4*)(Ep + ks * 32);
            const float4 v1 = *(const float4*)(Ep + ks * 32 + 4);
            union { unsigned short s[8]; bf16x8 v; } u;
            u.s[0] = f2bf(v0.x); u.s[1] = f2bf(v0.y);
            u.s[2] = f2bf(v0.z); u.s[3] = f2bf(v0.w);
            u.s[4] = f2bf(v1.x); u.s[5] = f2bf(v1.y);
            u.s[6] = f2bf(v1.z); u.s[7] = f2bf(v1.w);
            afr[ks] = u.v;
        }
    }

    float sc[4] = {0.f, 0.f, 0.f, 0.f};
    const float* biasb = bias + b * ATTN_D;
    const int swz = c & 7;

    __syncthreads();   // chunk 0 staged (vmcnt drained before barrier)

    for (int chunk = 0; chunk < 16; ++chunk) {
        // stage next chunk into the other buffer (async, overlaps compute)
        if (chunk < 15) {
            const char* gsrc = (const char*)WTsw + (size_t)(chunk + 1) * 32768;
            char* ldst = (char*)&wlds[(chunk + 1) & 1][0];
#pragma unroll
            for (int i = 0; i < 4; ++i)
                lds_cp16(ldst + i * 8192 + tid * 16, gsrc + i * 8192 + tid * 16);
        }

        const unsigned short* wb = &wlds[chunk & 1][0];
        f32x4 acc0 = {0.f, 0.f, 0.f, 0.f}, acc1 = {0.f, 0.f, 0.f, 0.f};
#pragma unroll
        for (int ks = 0; ks < 16; ++ks) {
            const int g = ks * 4 + quad;
            const int gs = (g ^ swz) * 8;
            bf16x8 b0 = *(const bf16x8*)(wb + c * 512 + gs);          // colc = c
            bf16x8 b1 = *(const bf16x8*)(wb + (16 + c) * 512 + gs);   // colc = 16+c
            acc0 = __builtin_amdgcn_mfma_f32_16x16x32_bf16(afr[ks], b0, acc0, 0, 0, 0);
            acc1 = __builtin_amdgcn_mfma_f32_16x16x32_bf16(afr[ks], b1, acc1, 0, 0, 0);
        }

        // epilogue: bias + relu + dot(W_comb)
        const int n0 = chunk * 32 + c;
        {
            const float bi = biasb[n0], wc = Wcomb[n0];
#pragma unroll
            for (int r = 0; r < 4; ++r) {
                float v = acc0[r] + bi;
                sc[r] += (v > 0.f ? v : 0.f) * wc;
            }
        }
        {
            const float bi = biasb[n0 + 16], wc = Wcomb[n0 + 16];
#pragma unroll
            for (int r = 0; r < 4; ++r) {
                float v = acc1[r] + bi;
                sc[r] += (v > 0.f ? v : 0.f) * wc;
            }
        }
        __syncthreads();   // drains staging; buffers safe to swap
    }

    // reduce across the 16 column-lanes
#pragma unroll
    for (int r = 0; r < 4; ++r) {
        float v = sc[r];
        v += __shfl_xor(v, 1);
        v += __shfl_xor(v, 2);
        v += __shfl_xor(v, 4);
        v += __shfl_xor(v, 8);
        sc[r] = v;
    }
    if (c == 0) {
        const int grow = r0 + w * 16 + quad * 4;
#pragma unroll
        for (int r = 0; r < 4; ++r) scores[grow + r] = sc[r];
    }
}

// ---------------------------------------------------------------------------
// Kernel 4: softmax over L=1024 per batch (in place)
// ---------------------------------------------------------------------------
__global__ __launch_bounds__(256) void k_softmax(float* __restrict__ s) {
    __shared__ float red[256];
    const int b = blockIdx.x, t = threadIdx.x;
    float v[4];
    float m = -1e30f;
#pragma unroll
    for (int i = 0; i < 4; ++i) {
        v[i] = s[b * SEQ + i * 256 + t];
        m = fmaxf(m, v[i]);
    }
    red[t] = m;
    __syncthreads();
    for (int o = 128; o > 0; o >>= 1) {
        if (t < o) red[t] = fmaxf(red[t], red[t + o]);
        __syncthreads();
    }
    m = red[0];
    __syncthreads();
    float sum = 0.f;
#pragma unroll
    for (int i = 0; i < 4; ++i) {
        v[i] = __expf(v[i] - m);
        sum += v[i];
    }
    red[t] = sum;
    __syncthreads();
    for (int o = 128; o > 0; o >>= 1) {
        if (t < o) red[t] += red[t + o];
        __syncthreads();
    }
    const float inv = 1.f / red[0];
#pragma unroll
    for (int i = 0; i < 4; ++i) s[b * SEQ + i * 256 + t] = v[i] * inv;
}

// ---------------------------------------------------------------------------
// Kernel 5: context partials. 1024 blocks x 128 threads. Block = (b, lo):
// 64 L-rows; lane owns a float4 of ENC. Fully coalesced 2 KB rows.
// ---------------------------------------------------------------------------
__global__ __launch_bounds__(128) void k_context(const float* __restrict__ E,
                                                 const float* __restrict__ wts,
                                                 float* __restrict__ part) {
    __shared__ float wl[64];
    const int blk = blockIdx.x, t = threadIdx.x;
    const int b = blk >> 4, lo = blk & 15;
    if (t < 64) wl[t] = wts[b * SEQ + lo * 64 + t];
    __syncthreads();
    const float* Ep = E + ((size_t)(b * SEQ + lo * 64)) * ENC_D + t * 4;
    f32x4 acc = {0.f, 0.f, 0.f, 0.f};
#pragma unroll 8
    for (int l = 0; l < 64; ++l) {
        const float4 v = *(const float4*)(Ep + (size_t)l * ENC_D);
        const float wv = wl[l];
        acc[0] += wv * v.x; acc[1] += wv * v.y;
        acc[2] += wv * v.z; acc[3] += wv * v.w;
    }
    *(f32x4*)(&part[(size_t)(b * 16 + lo) * ENC_D + t * 4]) = acc;
}

// ---------------------------------------------------------------------------
// Kernel 6: reduce 16 L-chunk partials -> out[b][e]
// ---------------------------------------------------------------------------
__global__ __launch_bounds__(256) void k_reduce(const float* __restrict__ part,
                                                float* __restrict__ out) {
    const int idx = blockIdx.x * 256 + threadIdx.x;  // 0..32767
    const int b = idx >> 9, e = idx & 511;
    const float* p = part + (size_t)b * 16 * ENC_D + e;
    float s = 0.f;
#pragma unroll
    for (int i = 0; i < 16; ++i) s += p[i * ENC_D];
    out[idx] = s;
}

// ---------------------------------------------------------------------------
extern "C" void kernel_launch(void* const* d_in, const int* in_sizes, int n_in,
                              void* d_out, int out_size, void* d_ws, size_t ws_size,
                              hipStream_t stream) {
    const float* E      = (const float*)d_in[0];
    const float* str    = (const float*)d_in[1];
    const float* cell   = (const float*)d_in[2];
    const float* Wenc   = (const float*)d_in[3];
    const float* b_enc  = (const float*)d_in[4];
    const float* Wstr   = (const float*)d_in[5];
    const float* b_str  = (const float*)d_in[6];
    const float* Wcell  = (const float*)d_in[7];
    const float* b_cell = (const float*)d_in[8];
    const float* Wcomb  = (const float*)d_in[9];
    // d_in[10] = b_comb: uniform pre-softmax shift — no effect, skipped.
    float* out = (float*)d_out;

    char* ws = (char*)d_ws;
    unsigned short* WT = (unsigned short*)ws;                 // 512 KB (swizzled)
    float* bias   = (float*)(ws + (512 << 10));               // 128 KB
    float* scores = (float*)(ws + (512 << 10) + (128 << 10)); // 256 KB
    float* part   = (float*)(ws + (512 << 10) + (128 << 10) + (256 << 10)); // 2 MB

    k_prep_wt<<<128, 256, 0, stream>>>(Wenc, WT);
    k_bias<<<64, 256, 0, stream>>>(str, cell, b_enc, Wstr, b_str, Wcell, b_cell, bias);
    k_scores<<<NROWS / 128, 512, 0, stream>>>(E, WT, bias, Wcomb, scores);
    k_softmax<<<BATCH, 256, 0, stream>>>(scores);
    k_context<<<1024, 128, 0, stream>>>(E, scores, part);
    k_reduce<<<NROWS / 512, 256, 0, stream>>>(part, out);
}

// Round 3
// 298.921 us; speedup vs baseline: 1.9116x; 1.2782x over previous
//
#include <hip/hip_runtime.h>
#include <stdint.h>

#define ENC_D 512
#define ATTN_D 512
#define STR_D 256
#define CELL_D 512
#define BATCH 64
#define SEQ 1024
#define NROWS (BATCH * SEQ)

typedef __bf16 bf16x8 __attribute__((ext_vector_type(8)));
typedef float f32x4 __attribute__((ext_vector_type(4)));

__device__ __forceinline__ unsigned short f2bf(float f) {
    unsigned int u = __float_as_uint(f);
    u += 0x7fffu + ((u >> 16) & 1u);   // RNE
    return (unsigned short)(u >> 16);
}

__device__ __forceinline__ void lds_cp16(void* l, const void* g) {
    __builtin_amdgcn_global_load_lds(
        (const __attribute__((address_space(1))) unsigned int*)g,
        (__attribute__((address_space(3))) unsigned int*)l, 16, 0, 0);
}

// ---------------------------------------------------------------------------
// Kernel 1: WT_sw — bf16(W_enc^T), pre-swizzled (granule = 8 k-elems, 16 B):
//   chunk = n>>5, colc = n&31, slot = colc*64 + (g ^ (colc&7)),  g = k/8
// LDS tile-transpose version: 64 blocks, each does a 64x64 tile.
// ---------------------------------------------------------------------------
__global__ __launch_bounds__(256) void k_prep_wt(const float* __restrict__ W,
                                                 unsigned short* __restrict__ WT) {
    __shared__ unsigned short T[64 * 68];      // [n_local][e_local], stride 68
    const int t = threadIdx.x;
    const int ei = blockIdx.x >> 3, ni = blockIdx.x & 7;
    const int e0 = ei * 64, n0 = ni * 64;

    // load 64x64 tile of W (row-major, coalesced float4), write transposed to LDS
#pragma unroll
    for (int i = 0; i < 4; ++i) {
        const int idx = t + i * 256;           // 0..1023
        const int r = idx >> 4, c4 = idx & 15; // row in tile, float4 col
        const float4 v = *(const float4*)(W + (size_t)(e0 + r) * ATTN_D + n0 + c4 * 4);
        T[(c4 * 4 + 0) * 68 + r] = f2bf(v.x);
        T[(c4 * 4 + 1) * 68 + r] = f2bf(v.y);
        T[(c4 * 4 + 2) * 68 + r] = f2bf(v.z);
        T[(c4 * 4 + 3) * 68 + r] = f2bf(v.w);
    }
    __syncthreads();

    // emit 16 B granules (8 consecutive e for one n) to swizzled global layout
#pragma unroll
    for (int i = 0; i < 2; ++i) {
        const int q = t + i * 256;             // 0..511 granules
        const int n = q >> 3, ge = q & 7;
        union { unsigned short s[8]; uint4 u; } o;
#pragma unroll
        for (int j = 0; j < 8; ++j) o.s[j] = T[n * 68 + ge * 8 + j];
        const int ng = n0 + n;
        const int g = ei * 8 + ge;             // global k-granule index
        const int chunk = ng >> 5, colc = ng & 31;
        const int slot = colc * 64 + (g ^ (colc & 7));
        *(uint4*)(WT + (size_t)chunk * 16384 + slot * 8) = o.u;
    }
}

// ---------------------------------------------------------------------------
// Kernel 2: bias[b][a] (fp32). 64 blocks x 256 threads.
// Thread (jh, a4): jh = j-half (wave-uniform), a4 = float4 column group.
// str/cell staged in LDS; float4 W loads; halves combined via LDS.
// ---------------------------------------------------------------------------
__global__ __launch_bounds__(256) void k_bias(const float* __restrict__ str,
                                              const float* __restrict__ cell,
                                              const float* __restrict__ b_enc,
                                              const float* __restrict__ Wstr,
                                              const float* __restrict__ b_str,
                                              const float* __restrict__ Wcell,
                                              const float* __restrict__ b_cell,
                                              float* __restrict__ bias) {
    __shared__ float sj[768];
    __shared__ f32x4 red[128];
    const int b = blockIdx.x, t = threadIdx.x;
#pragma unroll
    for (int i = 0; i < 3; ++i) {
        const int idx = t + i * 256;
        sj[idx] = (idx < 256) ? str[b * STR_D + idx] : cell[b * CELL_D + idx - 256];
    }
    __syncthreads();

    const int a4 = t & 127, jh = t >> 7;   // jh wave-uniform (waves 0,1 vs 2,3)
    f32x4 acc = {0.f, 0.f, 0.f, 0.f};
    if (jh == 0) {
        // str: j 0..255
#pragma unroll 8
        for (int j = 0; j < 256; ++j) {
            const float s = sj[j];
            const float4 wv = *(const float4*)(Wstr + (size_t)j * ATTN_D + a4 * 4);
            acc[0] += s * wv.x; acc[1] += s * wv.y; acc[2] += s * wv.z; acc[3] += s * wv.w;
        }
        // cell: j 0..127
#pragma unroll 8
        for (int j = 0; j < 128; ++j) {
            const float s = sj[256 + j];
            const float4 wv = *(const float4*)(Wcell + (size_t)j * ATTN_D + a4 * 4);
            acc[0] += s * wv.x; acc[1] += s * wv.y; acc[2] += s * wv.z; acc[3] += s * wv.w;
        }
    } else {
        // cell: j 128..511
#pragma unroll 8
        for (int j = 128; j < 512; ++j) {
            const float s = sj[256 + j];
            const float4 wv = *(const float4*)(Wcell + (size_t)j * ATTN_D + a4 * 4);
            acc[0] += s * wv.x; acc[1] += s * wv.y; acc[2] += s * wv.z; acc[3] += s * wv.w;
        }
        red[a4] = acc;
    }
    __syncthreads();
    if (jh == 0) {
        const f32x4 o = red[a4];
        const int a = a4 * 4;
        const float4 be = *(const float4*)(b_enc + a);
        const float4 bs = *(const float4*)(b_str + a);
        const float4 bc = *(const float4*)(b_cell + a);
        f32x4 r;
        r[0] = acc[0] + o[0] + be.x + bs.x + bc.x;
        r[1] = acc[1] + o[1] + be.y + bs.y + bc.y;
        r[2] = acc[2] + o[2] + be.z + bs.z + bc.z;
        r[3] = acc[3] + o[3] + be.w + bs.w + bc.w;
        *(f32x4*)(bias + b * ATTN_D + a) = r;
    }
}

// ---------------------------------------------------------------------------
// Kernel 3: fused scores GEMM. 512 blocks x 256 threads (4 waves), M=128/block.
// Wave owns 32 rows: A in registers (2 M-tiles x 16 ks x bf16x8 = 128 VGPRs).
// Per N-chunk (32 cols): 2 B-frags per ks feed 4 MFMAs (2x2) -> B-frag LDS
// traffic halved vs round 2 (0.5 KB/MFMA, cap ~30% MfmaUtil).
// ---------------------------------------------------------------------------
__global__ __launch_bounds__(256, 2) void k_scores(const float* __restrict__ E,
                                                   const unsigned short* __restrict__ WTsw,
                                                   const float* __restrict__ bias,
                                                   const float* __restrict__ Wcomb,
                                                   float* __restrict__ scores) {
    __shared__ unsigned short wlds[2][16384];   // 2 x 32 KB

    const int tid = threadIdx.x;
    const int r0 = blockIdx.x * 128;
    const int b = blockIdx.x >> 3;              // 8 blocks per batch
    const int w = tid >> 6, lane = tid & 63;
    const int quad = lane >> 4, c = lane & 15;

    // stage W chunk 0 (async): 32 KB, 256 threads x 16 B x 8
#pragma unroll
    for (int i = 0; i < 8; ++i)
        lds_cp16((char*)&wlds[0][0] + i * 4096 + tid * 16,
                 (const char*)WTsw + i * 4096 + tid * 16);

    // load A: 2 M-tiles x full K in registers
    bf16x8 afr[2][16];
#pragma unroll
    for (int m = 0; m < 2; ++m) {
        const float* Ep = E + (size_t)(r0 + w * 32 + m * 16 + c) * ENC_D + quad * 8;
#pragma unroll
        for (int ks = 0; ks < 16; ++ks) {
            const float4 v0 = *(const float4*)(Ep + ks * 32);
            const float4 v1 = *(const float4*)(Ep + ks * 32 + 4);
            union { unsigned short s[8]; bf16x8 v; } u;
            u.s[0] = f2bf(v0.x); u.s[1] = f2bf(v0.y);
            u.s[2] = f2bf(v0.z); u.s[3] = f2bf(v0.w);
            u.s[4] = f2bf(v1.x); u.s[5] = f2bf(v1.y);
            u.s[6] = f2bf(v1.z); u.s[7] = f2bf(v1.w);
            afr[m][ks] = u.v;
        }
    }

    float sc0[4] = {0.f, 0.f, 0.f, 0.f};
    float sc1[4] = {0.f, 0.f, 0.f, 0.f};
    const float* biasb = bias + b * ATTN_D;
    const int swz = c & 7;   // (16+c)&7 == c&7

    __syncthreads();

    for (int chunk = 0; chunk < 16; ++chunk) {
        if (chunk < 15) {
            const char* gsrc = (const char*)WTsw + (size_t)(chunk + 1) * 32768;
            char* ldst = (char*)&wlds[(chunk + 1) & 1][0];
#pragma unroll
            for (int i = 0; i < 8; ++i)
                lds_cp16(ldst + i * 4096 + tid * 16, gsrc + i * 4096 + tid * 16);
        }

        const unsigned short* wb = &wlds[chunk & 1][0];
        f32x4 a00 = {0.f,0.f,0.f,0.f}, a01 = {0.f,0.f,0.f,0.f};
        f32x4 a10 = {0.f,0.f,0.f,0.f}, a11 = {0.f,0.f,0.f,0.f};
#pragma unroll
        for (int ks = 0; ks < 16; ++ks) {
            const int gs = ((ks * 4 + quad) ^ swz) * 8;
            const bf16x8 b0 = *(const bf16x8*)(wb + c * 512 + gs);
            const bf16x8 b1 = *(const bf16x8*)(wb + (16 + c) * 512 + gs);
            a00 = __builtin_amdgcn_mfma_f32_16x16x32_bf16(afr[0][ks], b0, a00, 0, 0, 0);
            a10 = __builtin_amdgcn_mfma_f32_16x16x32_bf16(afr[1][ks], b0, a10, 0, 0, 0);
            a01 = __builtin_amdgcn_mfma_f32_16x16x32_bf16(afr[0][ks], b1, a01, 0, 0, 0);
            a11 = __builtin_amdgcn_mfma_f32_16x16x32_bf16(afr[1][ks], b1, a11, 0, 0, 0);
        }

        const int n0 = chunk * 32 + c;
        const float bi0 = biasb[n0], wc0 = Wcomb[n0];
        const float bi1 = biasb[n0 + 16], wc1 = Wcomb[n0 + 16];
#pragma unroll
        for (int r = 0; r < 4; ++r) {
            float v;
            v = a00[r] + bi0; sc0[r] += (v > 0.f ? v : 0.f) * wc0;
            v = a01[r] + bi1; sc0[r] += (v > 0.f ? v : 0.f) * wc1;
            v = a10[r] + bi0; sc1[r] += (v > 0.f ? v : 0.f) * wc0;
            v = a11[r] + bi1; sc1[r] += (v > 0.f ? v : 0.f) * wc1;
        }
        __syncthreads();
    }

    // reduce across the 16 column-lanes
#pragma unroll
    for (int r = 0; r < 4; ++r) {
        float v0 = sc0[r], v1 = sc1[r];
        v0 += __shfl_xor(v0, 1); v1 += __shfl_xor(v1, 1);
        v0 += __shfl_xor(v0, 2); v1 += __shfl_xor(v1, 2);
        v0 += __shfl_xor(v0, 4); v1 += __shfl_xor(v1, 4);
        v0 += __shfl_xor(v0, 8); v1 += __shfl_xor(v1, 8);
        sc0[r] = v0; sc1[r] = v1;
    }
    if (c == 0) {
        const int g0 = r0 + w * 32 + quad * 4;
#pragma unroll
        for (int r = 0; r < 4; ++r) scores[g0 + r] = sc0[r];
#pragma unroll
        for (int r = 0; r < 4; ++r) scores[g0 + 16 + r] = sc1[r];
    }
}

// ---------------------------------------------------------------------------
// Kernel 4: softmax over L=1024 per batch (in place)
// ---------------------------------------------------------------------------
__global__ __launch_bounds__(256) void k_softmax(float* __restrict__ s) {
    __shared__ float red[256];
    const int b = blockIdx.x, t = threadIdx.x;
    float v[4];
    float m = -1e30f;
#pragma unroll
    for (int i = 0; i < 4; ++i) {
        v[i] = s[b * SEQ + i * 256 + t];
        m = fmaxf(m, v[i]);
    }
    red[t] = m;
    __syncthreads();
    for (int o = 128; o > 0; o >>= 1) {
        if (t < o) red[t] = fmaxf(red[t], red[t + o]);
        __syncthreads();
    }
    m = red[0];
    __syncthreads();
    float sum = 0.f;
#pragma unroll
    for (int i = 0; i < 4; ++i) {
        v[i] = __expf(v[i] - m);
        sum += v[i];
    }
    red[t] = sum;
    __syncthreads();
    for (int o = 128; o > 0; o >>= 1) {
        if (t < o) red[t] += red[t + o];
        __syncthreads();
    }
    const float inv = 1.f / red[0];
#pragma unroll
    for (int i = 0; i < 4; ++i) s[b * SEQ + i * 256 + t] = v[i] * inv;
}

// ---------------------------------------------------------------------------
// Kernel 5: context partials. 1024 blocks x 128 threads, 64 L-rows per block.
// ---------------------------------------------------------------------------
__global__ __launch_bounds__(128) void k_context(const float* __restrict__ E,
                                                 const float* __restrict__ wts,
                                                 float* __restrict__ part) {
    __shared__ float wl[64];
    const int blk = blockIdx.x, t = threadIdx.x;
    const int b = blk >> 4, lo = blk & 15;
    if (t < 64) wl[t] = wts[b * SEQ + lo * 64 + t];
    __syncthreads();
    const float* Ep = E + ((size_t)(b * SEQ + lo * 64)) * ENC_D + t * 4;
    f32x4 acc = {0.f, 0.f, 0.f, 0.f};
#pragma unroll 8
    for (int l = 0; l < 64; ++l) {
        const float4 v = *(const float4*)(Ep + (size_t)l * ENC_D);
        const float wv = wl[l];
        acc[0] += wv * v.x; acc[1] += wv * v.y;
        acc[2] += wv * v.z; acc[3] += wv * v.w;
    }
    *(f32x4*)(&part[(size_t)(b * 16 + lo) * ENC_D + t * 4]) = acc;
}

// ---------------------------------------------------------------------------
// Kernel 6: reduce 16 L-chunk partials -> out[b][e]
// ---------------------------------------------------------------------------
__global__ __launch_bounds__(256) void k_reduce(const float* __restrict__ part,
                                                float* __restrict__ out) {
    const int idx = blockIdx.x * 256 + threadIdx.x;  // 0..32767
    const int b = idx >> 9, e = idx & 511;
    const float* p = part + (size_t)b * 16 * ENC_D + e;
    float s = 0.f;
#pragma unroll
    for (int i = 0; i < 16; ++i) s += p[i * ENC_D];
    out[idx] = s;
}

// ---------------------------------------------------------------------------
extern "C" void kernel_launch(void* const* d_in, const int* in_sizes, int n_in,
                              void* d_out, int out_size, void* d_ws, size_t ws_size,
                              hipStream_t stream) {
    const float* E      = (const float*)d_in[0];
    const float* str    = (const float*)d_in[1];
    const float* cell   = (const float*)d_in[2];
    const float* Wenc   = (const float*)d_in[3];
    const float* b_enc  = (const float*)d_in[4];
    const float* Wstr   = (const float*)d_in[5];
    const float* b_str  = (const float*)d_in[6];
    const float* Wcell  = (const float*)d_in[7];
    const float* b_cell = (const float*)d_in[8];
    const float* Wcomb  = (const float*)d_in[9];
    // d_in[10] = b_comb: uniform pre-softmax shift — no effect, skipped.
    float* out = (float*)d_out;

    char* ws = (char*)d_ws;
    unsigned short* WT = (unsigned short*)ws;                 // 512 KB (swizzled)
    float* bias   = (float*)(ws + (512 << 10));               // 128 KB
    float* scores = (float*)(ws + (512 << 10) + (128 << 10)); // 256 KB
    float* part   = (float*)(ws + (512 << 10) + (128 << 10) + (256 << 10)); // 2 MB

    k_prep_wt<<<64, 256, 0, stream>>>(Wenc, WT);
    k_bias<<<64, 256, 0, stream>>>(str, cell, b_enc, Wstr, b_str, Wcell, b_cell, bias);
    k_scores<<<NROWS / 128, 256, 0, stream>>>(E, WT, bias, Wcomb, scores);
    k_softmax<<<BATCH, 256, 0, stream>>>(scores);
    k_context<<<1024, 128, 0, stream>>>(E, scores, part);
    k_reduce<<<NROWS / 512, 256, 0, stream>>>(part, out);
}